// Round 1
// baseline (183.474 us; speedup 1.0000x reference)
//
#include <hip/hip_runtime.h>
#include <stdint.h>

#define B_DIM 8192
#define H_DIM 1024
#define E_DIM 300
#define A_DIM 512
#define KP    1920   // 1024 + 320(pad 300) + 512 + 64 zero-pad = 30*64 (even #tiles)
#define KE0   1024   // start of embedding segment
#define KA0   1344   // start of context segment
#define KA1   1856   // end of context segment (rest zero)
#define BK    64
#define NT    30     // K tiles
#define NITER 15     // 2 tiles per iteration

typedef __bf16 bf16;
typedef bf16  bf16x8 __attribute__((ext_vector_type(8)));
typedef float f32x4  __attribute__((ext_vector_type(4)));

__device__ __forceinline__ uint16_t f2bf(float f) {
  uint32_t u = __float_as_uint(f);
  u += 0x7fff + ((u >> 16) & 1);   // round-to-nearest-even
  return (uint16_t)(u >> 16);
}

// ---- pack X = [B][KP] bf16 : [h | emb | pad | ctx | pad] ----
__global__ void pack_x_kernel(const float* __restrict__ h,
                              const float* __restrict__ e,
                              const float* __restrict__ a,
                              uint16_t* __restrict__ X) {
  int idx = blockIdx.x * blockDim.x + threadIdx.x;
  const int gpr = KP / 8;                 // 240 groups per row
  if (idx >= B_DIM * gpr) return;
  int row  = idx / gpr;
  int col0 = (idx % gpr) * 8;
  __align__(16) uint16_t v[8];
#pragma unroll
  for (int j = 0; j < 8; ++j) {
    int c = col0 + j;
    float x;
    if (c < KE0) x = h[(size_t)row * H_DIM + c];
    else if (c < KA0) {
      int ce = c - KE0;
      x = (ce < E_DIM) ? e[(size_t)row * E_DIM + ce] : 0.f;
    } else if (c < KA1) x = a[(size_t)row * A_DIM + (c - KA0)];
    else x = 0.f;
    v[j] = f2bf(x);
  }
  *(uint4*)(X + (size_t)row * KP + col0) = *(const uint4*)v;
}

// ---- pack W = [4096][KP] bf16, gate-interleaved at 64-unit granularity:
//      packed row = (o>>6)*256 + g*64 + (o&63)  for source row g*1024+o.
//      A 256-col GEMM tile then holds all 4 gates for 64 units. ----
__global__ void pack_w_kernel(const float* __restrict__ Wh,
                              const float* __restrict__ Wx,
                              const float* __restrict__ Wa,
                              uint16_t* __restrict__ W) {
  int idx = blockIdx.x * blockDim.x + threadIdx.x;
  const int gpr = KP / 8;
  if (idx >= 4096 * gpr) return;
  int pr   = idx / gpr;                   // packed row
  int col0 = (idx % gpr) * 8;
  int ub = pr >> 8, g = (pr >> 6) & 3, ui = pr & 63;
  size_t srow = (size_t)(g * H_DIM + ub * 64 + ui);
  __align__(16) uint16_t v[8];
#pragma unroll
  for (int j = 0; j < 8; ++j) {
    int c = col0 + j;
    float x;
    if (c < KE0) x = Wh[srow * H_DIM + c];
    else if (c < KA0) {
      int ce = c - KE0;
      x = (ce < E_DIM) ? Wx[srow * E_DIM + ce] : 0.f;
    } else if (c < KA1) x = Wa[srow * A_DIM + (c - KA0)];
    else x = 0.f;
    v[j] = f2bf(x);
  }
  *(uint4*)(W + (size_t)pr * KP + col0) = *(const uint4*)v;
}

__device__ __forceinline__ void async_copy16(const void* g, void* l) {
  __builtin_amdgcn_global_load_lds(
      (__attribute__((address_space(1))) void*)g,
      (__attribute__((address_space(3))) void*)l, 16, 0, 0);
}

#define WAITV4 asm volatile("s_waitcnt vmcnt(4)" ::: "memory")
#define WAITV0 asm volatile("s_waitcnt vmcnt(0)" ::: "memory")

// One 8-phase sub-phase: ds-read frags, issue prefetch, barrier, lgkm drain,
// 16 MFMA under setprio, optional counted-vmcnt at tile boundary, barrier.
#define PHASE(BUF, MP, PRE, TW)                                                              \
  {                                                                                          \
    bf16x8 a00 = *(const bf16x8*)(Ard0 + (BUF)*16384 + (2*(MP))*1024);                       \
    bf16x8 a01 = *(const bf16x8*)(Ard1 + (BUF)*16384 + (2*(MP))*1024);                       \
    bf16x8 a10 = *(const bf16x8*)(Ard0 + (BUF)*16384 + (2*(MP)+1)*1024);                     \
    bf16x8 a11 = *(const bf16x8*)(Ard1 + (BUF)*16384 + (2*(MP)+1)*1024);                     \
    if ((MP) == 0) {                                                                         \
      _Pragma("unroll")                                                                      \
      for (int n_ = 0; n_ < 4; ++n_) {                                                       \
        bfr[n_][0] = *(const bf16x8*)(Brd0 + (BUF)*16384 + n_*1024);                         \
        bfr[n_][1] = *(const bf16x8*)(Brd1 + (BUF)*16384 + n_*1024);                         \
      }                                                                                      \
    }                                                                                        \
    PRE;                                                                                     \
    __builtin_amdgcn_s_barrier();                                                            \
    asm volatile("s_waitcnt lgkmcnt(0)" ::: "memory");                                       \
    __builtin_amdgcn_s_setprio(1);                                                           \
    _Pragma("unroll")                                                                        \
    for (int n_ = 0; n_ < 4; ++n_) {                                                         \
      acc[2*(MP)][n_]   = __builtin_amdgcn_mfma_f32_16x16x32_bf16(a00, bfr[n_][0], acc[2*(MP)][n_],   0, 0, 0); \
      acc[2*(MP)+1][n_] = __builtin_amdgcn_mfma_f32_16x16x32_bf16(a10, bfr[n_][0], acc[2*(MP)+1][n_], 0, 0, 0); \
      acc[2*(MP)][n_]   = __builtin_amdgcn_mfma_f32_16x16x32_bf16(a01, bfr[n_][1], acc[2*(MP)][n_],   0, 0, 0); \
      acc[2*(MP)+1][n_] = __builtin_amdgcn_mfma_f32_16x16x32_bf16(a11, bfr[n_][1], acc[2*(MP)+1][n_], 0, 0, 0); \
    }                                                                                        \
    __builtin_amdgcn_s_setprio(0);                                                           \
    TW;                                                                                      \
    __builtin_amdgcn_s_barrier();                                                            \
  }

// ---- fused GEMM + gates: 256x256 tile, 8 waves (2Mx4N), BK=64, 8-phase
//      counted-vmcnt pipeline (T3+T4), setprio (T5), chunk-XOR LDS swizzle (T2).
//      Wave wc owns gate wc for 64 units; epilogue fused through LDS. ----
__global__ __launch_bounds__(512, 2) void lstm_fused_kernel(
    const uint16_t* __restrict__ X, const uint16_t* __restrict__ W,
    const float* __restrict__ c_prev,
    const float* __restrict__ b0, const float* __restrict__ b1,
    const float* __restrict__ b2, const float* __restrict__ b3,
    float* __restrict__ out) {
  __shared__ __align__(16) uint16_t smem[4 * 256 * 64];  // 128 KiB
  uint16_t* As = smem;                  // [2][256][64] swizzled
  uint16_t* Bs = smem + 2 * 256 * 64;   // [2][256][64] swizzled

  const int t    = threadIdx.x;
  const int lane = t & 63;
  const int wid  = t >> 6;
  const int wr   = wid >> 2;            // 0..1 : row half
  const int wc   = wid & 3;             // 0..3 : gate / 64-col block
  const int lr   = lane & 15;
  const int kh   = lane >> 4;
  const int m0   = blockIdx.x * 256;
  const int by   = blockIdx.y;          // 64-unit block
  const int n0   = by * 256;            // packed-W row base

  // bias folded into accumulator init (gate = wc, unit = by*64 + n*16 + lr)
  f32x4 acc[8][4];
#pragma unroll
  for (int n = 0; n < 4; ++n) {
    int bidx = wc * H_DIM + by * 64 + n * 16 + lr;
    float bs = b0[bidx] + b1[bidx] + b2[bidx] + b3[bidx];
#pragma unroll
    for (int m = 0; m < 8; ++m) acc[m][n] = (f32x4){bs, bs, bs, bs};
  }

  // staging: 512 thr x 16B = 8 KB = 64 rows x 64 cols per issue; 2 issues/half-tile.
  // Linear LDS dest (= base + t*16B); global source chunk pre-XOR-swizzled by row&7.
  const int sr   = t >> 3;                          // row within 64-row issue
  const int csrc = (((t & 7) ^ (sr & 7)) * 8);      // pre-swizzled source chunk

  auto stageA = [&](int kt, int hf, int buf) {
#pragma unroll
    for (int l_ = 0; l_ < 2; ++l_)
      async_copy16(X + (size_t)(m0 + hf * 128 + l_ * 64 + sr) * KP + kt * BK + csrc,
                   As + buf * 16384 + (hf * 128 + l_ * 64) * 64 + t * 8);
  };
  auto stageB = [&](int kt, int hf, int buf) {
#pragma unroll
    for (int l_ = 0; l_ < 2; ++l_)
      async_copy16(W + (size_t)(n0 + hf * 128 + l_ * 64 + sr) * KP + kt * BK + csrc,
                   Bs + buf * 16384 + (hf * 128 + l_ * 64) * 64 + t * 8);
  };

  // ds_read bases: row = (wr*128|wc*64) + frag + lr, chunk = (kk*4+kh) ^ (row&7)
  const int ck0 = (kh ^ (lr & 7)) * 8;
  const uint16_t* Ard0 = As + (wr * 128 + lr) * 64 + ck0;
  const uint16_t* Ard1 = As + (wr * 128 + lr) * 64 + (ck0 ^ 32);
  const uint16_t* Brd0 = Bs + (wc * 64 + lr) * 64 + ck0;
  const uint16_t* Brd1 = Bs + (wc * 64 + lr) * 64 + (ck0 ^ 32);

  bf16x8 bfr[4][2];

  // prologue: stage B(0),A(0)->buf0, B(1)->buf1; drain all but newest 2 half-tiles
  stageB(0, 0, 0); stageB(0, 1, 0);
  stageA(0, 0, 0); stageA(0, 1, 0);
  stageB(1, 0, 1); stageB(1, 1, 1);
  WAITV4;
  __builtin_amdgcn_s_barrier();

  // Steady state per iter (tiles 2i->buf0, 2i+1->buf1):
  //  P1:A(2i+1)h0  P2:A(2i+1)h1  P3:B(2i+2)h0  P4:B(2i+2)h1 +vmcnt(4)
  //  P5:A(2i+2)h0  P6:A(2i+2)h1  P7:B(2i+3)h0  P8:B(2i+3)h1 +vmcnt(4)
  // Each buffer region is re-staged only after the barrier following its last read
  // (B: phase 1 of its tile; A: phase 4). vmcnt(4) = 2 half-tiles in flight.
#pragma unroll 1
  for (int it = 0; it < NITER; ++it) {
    const int kt = 2 * it;
    const bool ntail = (it < NITER - 1);
    PHASE(0, 0, stageA(kt + 1, 0, 1), (void)0)
    PHASE(0, 1, stageA(kt + 1, 1, 1), (void)0)
    PHASE(0, 2, if (ntail) stageB(kt + 2, 0, 0), (void)0)
    PHASE(0, 3, if (ntail) stageB(kt + 2, 1, 0),
          if (ntail) { WAITV4; } else { WAITV0; })
    PHASE(1, 0, if (ntail) stageA(kt + 2, 0, 0), (void)0)
    PHASE(1, 1, if (ntail) stageA(kt + 2, 1, 0), (void)0)
    PHASE(1, 2, if (ntail) stageB(kt + 3, 0, 1), (void)0)
    PHASE(1, 3, if (ntail) stageB(kt + 3, 1, 1),
          if (ntail) { WAITV4; })
  }

  // ---- fused epilogue: two 128-row rounds through 128 KiB LDS as pre[128][256].
  //      col XOR'd with ((row>>2)&3)<<4 -> 2-way (free) bank aliasing both sides. ----
  float* pre  = (float*)smem;
  float* outh = out;
  float* outc = out + (size_t)B_DIM * H_DIM;
  const int eu   = lane;        // unit within 64-block
  const int wrow = wid * 16;
#pragma unroll 1
  for (int ph = 0; ph < 2; ++ph) {
    if (wr == ph) {
#pragma unroll
      for (int m = 0; m < 8; ++m)
#pragma unroll
        for (int n = 0; n < 4; ++n) {
          int row = m * 16 + kh * 4;
          int col = (wc * 64 + n * 16 + lr) ^ (kh << 4);
#pragma unroll
          for (int j = 0; j < 4; ++j)
            pre[(row + j) * 256 + col] = acc[m][n][j];
        }
    }
    __syncthreads();
#pragma unroll 1
    for (int q = 0; q < 16; ++q) {
      int r   = wrow + q;
      int swz = (r & 12) << 2;            // ((r>>2)&3)<<4
      int ec  = eu ^ swz;
      float pi = pre[r * 256 + ec];
      float pf = pre[r * 256 + 64 + ec];
      float po = pre[r * 256 + 128 + ec];
      float pg = pre[r * 256 + 192 + ec];
      size_t o = (size_t)(m0 + ph * 128 + r) * H_DIM + by * 64 + eu;
      float cp = c_prev[o];
      float iv = 1.f / (1.f + __expf(-pi));
      float fv = 1.f / (1.f + __expf(-pf));
      float ov = 1.f / (1.f + __expf(-po));
      float gv = tanhf(pg);
      float ct = fv * cp + iv * gv;
      float ht = ov * tanhf(ct);
      outh[o] = ht;
      outc[o] = ct;
    }
    __syncthreads();
  }
}

extern "C" void kernel_launch(void* const* d_in, const int* in_sizes, int n_in,
                              void* d_out, int out_size, void* d_ws, size_t ws_size,
                              hipStream_t stream) {
  const float* h_prev = (const float*)d_in[0];
  const float* c_prev = (const float*)d_in[1];
  const float* emb    = (const float*)d_in[2];
  const float* ctx    = (const float*)d_in[3];
  const float* Wh     = (const float*)d_in[4];
  const float* Wx     = (const float*)d_in[5];
  const float* Wa     = (const float*)d_in[6];
  const float* bl     = (const float*)d_in[7];
  const float* bl2    = (const float*)d_in[8];
  const float* bl3    = (const float*)d_in[9];
  const float* bp     = (const float*)d_in[10];

  uint16_t* X = (uint16_t*)d_ws;                                   // 31.5 MB
  uint16_t* W = (uint16_t*)((char*)d_ws + (size_t)B_DIM * KP * 2); // 15.7 MB
  float* out = (float*)d_out;

  {
    int total = B_DIM * (KP / 8);
    pack_x_kernel<<<(total + 255) / 256, 256, 0, stream>>>(h_prev, emb, ctx, X);
  }
  {
    int total = 4096 * (KP / 8);
    pack_w_kernel<<<(total + 255) / 256, 256, 0, stream>>>(Wh, Wx, Wa, W);
  }
  dim3 grid(B_DIM / 256, 4096 / 256);   // (32, 16)
  lstm_fused_kernel<<<grid, 512, 0, stream>>>(X, W, c_prev, bl, bl2, bl3, bp, out);
}